// Round 10
// baseline (5305.396 us; speedup 1.0000x reference)
//
#include <hip/hip_runtime.h>
#include <hip/hip_bf16.h>
#include <stdint.h>
#include <math.h>

#define NB 128
#define NN 200
#define ND 128
#define NH 8
#define DH 16
#define NL 3
#define NF 2048
#define NT (NB * NN)
#define NSTEP 399

// ---------------- Threefry-2x32 (JAX-compatible) ----------------
__host__ __device__ inline void tf2x32(unsigned k0, unsigned k1, unsigned x0, unsigned x1,
                                       unsigned* o0, unsigned* o1) {
  unsigned ks[3] = {k0, k1, k0 ^ k1 ^ 0x1BD11BDAu};
  x0 += ks[0]; x1 += ks[1];
  const unsigned R[2][4] = {{13u, 15u, 26u, 6u}, {17u, 29u, 16u, 24u}};
#pragma unroll
  for (int i = 0; i < 5; ++i) {
#pragma unroll
    for (int j = 0; j < 4; ++j) {
      unsigned r = R[i & 1][j];
      x0 += x1;
      x1 = (x1 << r) | (x1 >> (32u - r));
      x1 ^= x0;
    }
    x0 += ks[(i + 1) % 3];
    x1 += ks[(i + 2) % 3] + (unsigned)(i + 1);
  }
  *o0 = x0; *o1 = x1;
}

__global__ void k_rng(unsigned* __restrict__ rng) {
  unsigned k0 = 0u, k1 = 42u;
  for (int t = 0; t < NSTEP; ++t) {
    unsigned a0, a1, s0, s1;
    tf2x32(k0, k1, 0u, 1u, &s0, &s1);
    tf2x32(k0, k1, 0u, 0u, &a0, &a1);
    rng[2 * t] = s0; rng[2 * t + 1] = s1;
    k0 = a0; k1 = a1;
  }
}

__global__ __launch_bounds__(256) void k_gum(const unsigned* __restrict__ rng, float* __restrict__ gum) {
  int idx = blockIdx.x * 256 + threadIdx.x;
  if (idx >= NSTEP * NT) return;
  int t = idx / NT, j = idx - t * NT;
  unsigned o0, o1;
  tf2x32(rng[2 * t], rng[2 * t + 1], 0u, (unsigned)j, &o0, &o1);
  unsigned bits = o0 ^ o1;
  float u01 = __uint_as_float((bits >> 9) | 0x3f800000u) - 1.0f;
  float uu = fmaxf(1.17549435082228751e-38f, u01);
  gum[idx] = (float)(-log(-log((double)uu)));
}

// ---------------- transpose f32->f32 (kept for misc) ----------------
__global__ void k_tr(const float* __restrict__ src, float* __restrict__ dst, int R, int C) {
  int i = blockIdx.x * 256 + threadIdx.x;
  if (i >= R * C) return;
  int c = i / R, r = i - c * R;
  dst[i] = src[(size_t)r * C + c];
}

// ---------------- transpose + lossless f32->f64 convert ----------------
__global__ void k_trd(const float* __restrict__ src, double* __restrict__ dst, int R, int C) {
  int i = blockIdx.x * 256 + threadIdx.x;
  if (i >= R * C) return;
  int c = i / R, r = i - c * R;
  dst[i] = (double)src[(size_t)r * C + c];
}

// ---------------- embed ----------------
__global__ void k_embed(const float* __restrict__ coords, const float* __restrict__ dem,
                        const float* __restrict__ cap, const float* __restrict__ eW,
                        const float* __restrict__ eb, float* __restrict__ h, float* __restrict__ dr) {
  int gid = blockIdx.x * blockDim.x + threadIdx.x;
  int t = gid >> 7, d = gid & 127;
  int b = t / NN;
  float drv = dem[t] / cap[b];
  double acc = (double)eW[d * 3] * (double)coords[2 * t]
             + (double)eW[d * 3 + 1] * (double)coords[2 * t + 1]
             + (double)eW[d * 3 + 2] * (double)drv;
  h[gid] = (float)acc + eb[d];
  if (d == 0) dr[t] = drv;
}

// ---------------- qkv: 8 tokens/block, f64 weights ----------------
#define QT 8
__global__ __launch_bounds__(384) void k_qkv(const float* __restrict__ h, const double* __restrict__ WT,
                                             const float* __restrict__ bias, float* __restrict__ qkv) {
  const int t0 = blockIdx.x * QT, j = threadIdx.x;
  __shared__ double hsh[ND][QT];
  for (int idx = j; idx < ND * QT; idx += 384) {
    int t = idx & 7, k = idx >> 3;
    hsh[k][t] = (double)h[(size_t)(t0 + t) * ND + k];
  }
  __syncthreads();
  double acc[QT];
#pragma unroll
  for (int t = 0; t < QT; ++t) acc[t] = 0.0;
  for (int k = 0; k < ND; ++k) {
    double w = WT[(size_t)k * 384 + j];
#pragma unroll
    for (int t = 0; t < QT; ++t) acc[t] += w * hsh[k][t];
  }
  float bv = bias[j];
#pragma unroll
  for (int t = 0; t < QT; ++t)
    qkv[(size_t)(t0 + t) * 384 + j] = (float)acc[t] + bv;
}

// ---------------- attention: wave-per-qn, ONE barrier ----------------
__global__ __launch_bounds__(256) void k_attn(const float* __restrict__ qkv, float* __restrict__ att) {
  const int b = blockIdx.x / NH, hh = blockIdx.x % NH, tid = threadIdx.x;
  const int lane = tid & 63, w = tid >> 6;
  __shared__ float qsh[NN][DH + 1];
  __shared__ float ksh[NN][DH + 1];
  __shared__ float vsh[NN][DH + 1];
  __shared__ float ashw[4][NN + 8];
  for (int idx = tid; idx < NN * DH; idx += 256) {
    int n = idx / DH, d2 = idx % DH;
    size_t base = (size_t)(b * NN + n) * 384 + hh * DH + d2;
    qsh[n][d2] = qkv[base];
    ksh[n][d2] = qkv[base + ND];
    vsh[n][d2] = qkv[base + 2 * ND];
  }
  __syncthreads();
  const int dd = lane & 15, q4 = lane >> 4;
  for (int qn = w; qn < NN; qn += 4) {
    double qv[DH];
#pragma unroll
    for (int d = 0; d < DH; ++d) qv[d] = (double)qsh[qn][d];
    float sf[4];
#pragma unroll
    for (int s = 0; s < 4; ++s) {
      int n = lane + 64 * s;
      if (n < NN) {
        double a = 0.0;
#pragma unroll
        for (int d = 0; d < DH; ++d) a += qv[d] * (double)ksh[n][d];
        sf[s] = (float)a / 4.0f;
      } else sf[s] = -3.0e38f;
    }
    float m = fmaxf(fmaxf(sf[0], sf[1]), fmaxf(sf[2], sf[3]));
    for (int off = 1; off < 64; off <<= 1) m = fmaxf(m, __shfl_xor(m, off, 64));
    double e[4];
    double esum = 0.0;
#pragma unroll
    for (int s = 0; s < 4; ++s) {
      int n = lane + 64 * s;
      e[s] = (n < NN) ? exp((double)(sf[s] - m)) : 0.0;
      esum += e[s];
    }
    for (int off = 1; off < 64; off <<= 1) esum += __shfl_xor(esum, off, 64);
#pragma unroll
    for (int s = 0; s < 4; ++s) {
      int n = lane + 64 * s;
      if (n < NN) ashw[w][n] = (float)(e[s] / esum);
    }
    double o = 0.0;
    for (int i = 0; i < 50; ++i) {
      int n = q4 * 50 + i;
      o += (double)ashw[w][n] * (double)vsh[n][dd];
    }
    o += __shfl_xor(o, 16, 64);
    o += __shfl_xor(o, 32, 64);
    if (lane < DH)
      att[(size_t)(b * NN + qn) * ND + hh * DH + lane] = (float)o;
  }
}

// ---------------- o-proj + residual + LN1, f64 weights ----------------
#define OT 4
__global__ __launch_bounds__(128) void k_oln(const float* __restrict__ att, const double* __restrict__ WoT,
                                             const float* __restrict__ bo, const float* __restrict__ g,
                                             const float* __restrict__ bb, float* __restrict__ h) {
  const int t0 = blockIdx.x * OT, d = threadIdx.x;
  __shared__ double ash[ND][OT];
  __shared__ float xsh[OT][ND];
  __shared__ float mred[OT], sred[OT];
  for (int idx = d; idx < ND * OT; idx += 128) {
    int t = idx & 3, k = idx >> 2;
    ash[k][t] = (double)att[(size_t)(t0 + t) * ND + k];
  }
  __syncthreads();
  double acc[OT];
#pragma unroll
  for (int t = 0; t < OT; ++t) acc[t] = 0.0;
  for (int k = 0; k < ND; ++k) {
    double w = WoT[(size_t)k * ND + d];
#pragma unroll
    for (int t = 0; t < OT; ++t) acc[t] += w * ash[k][t];
  }
  float bv = bo[d];
#pragma unroll
  for (int t = 0; t < OT; ++t) {
    float o = (float)acc[t] + bv;
    xsh[t][d] = h[(size_t)(t0 + t) * ND + d] + o;
  }
  __syncthreads();
  if (d < OT) {
    double sv = 0.0;
    for (int k = 0; k < ND; ++k) sv += (double)xsh[d][k];
    float m = (float)(sv / 128.0);
    double sq = 0.0;
    for (int k = 0; k < ND; ++k) { float tf = xsh[d][k] - m; sq += (double)tf * (double)tf; }
    mred[d] = m;
    sred[d] = sqrtf((float)(sq / 128.0) + 1e-5f);
  }
  __syncthreads();
#pragma unroll
  for (int t = 0; t < OT; ++t) {
    float tf = xsh[t][d] - mred[t];
    h[(size_t)(t0 + t) * ND + d] = tf / sred[t] * g[d] + bb[d];
  }
}

// ---------------- FFN + residual + LN2: FT=8, f64 weights (no cvt in hot loops) ----------------
#define FT 8
#define JC 1024
__global__ __launch_bounds__(256) void k_ffn(float* __restrict__ h, const double* __restrict__ W1T,
                                             const float* __restrict__ b1, const double* __restrict__ W2T,
                                             const float* __restrict__ b2, const float* __restrict__ g,
                                             const float* __restrict__ bb) {
  const int t0 = blockIdx.x * FT, tid = threadIdx.x;
  __shared__ double hsh[ND][FT];
  __shared__ double fsh[FT][JC];
  __shared__ float xsh[FT][ND];
  __shared__ float mred[FT], sred[FT];
  for (int idx = tid; idx < ND * FT; idx += 256) {
    int t = idx & 7, k = idx >> 3;
    hsh[k][t] = (double)h[(size_t)(t0 + t) * ND + k];
  }
  __syncthreads();
  const int jg = tid >> 5, dl = tid & 31;
  double acc2[4][FT];
#pragma unroll
  for (int a = 0; a < 4; ++a)
#pragma unroll
    for (int t = 0; t < FT; ++t) acc2[a][t] = 0.0;
  for (int c = 0; c < 2; ++c) {
    {
      const int j0 = tid * 4;
      double acc[4][FT];
#pragma unroll
      for (int a = 0; a < 4; ++a)
#pragma unroll
        for (int t = 0; t < FT; ++t) acc[a][t] = 0.0;
      for (int k = 0; k < ND; ++k) {
        double hv[FT];
#pragma unroll
        for (int t = 0; t < FT; ++t) hv[t] = hsh[k][t];
        const double* wp = W1T + (size_t)k * NF + c * JC + j0;
        double2 wa = *(const double2*)wp;
        double2 wb = *(const double2*)(wp + 2);
        double wd[4] = {wa.x, wa.y, wb.x, wb.y};
#pragma unroll
        for (int a = 0; a < 4; ++a)
#pragma unroll
          for (int t = 0; t < FT; ++t) acc[a][t] += wd[a] * hv[t];
      }
#pragma unroll
      for (int a = 0; a < 4; ++a) {
        float bv = b1[c * JC + j0 + a];
#pragma unroll
        for (int t = 0; t < FT; ++t) {
          float f = (float)acc[a][t] + bv;   // f32 round at tensor boundary (exact)
          fsh[t][j0 + a] = (double)fmaxf(f, 0.0f);
        }
      }
    }
    __syncthreads();
    for (int i = 0; i < 128; ++i) {
      int jj = (jg << 7) | ((i + jg) & 127);
      int j = c * JC + jj;
      double fv[FT];
#pragma unroll
      for (int t = 0; t < FT; ++t) fv[t] = fsh[t][jj];
      const double* wp = W2T + (size_t)j * ND + (dl << 2);
      double2 w01 = *(const double2*)wp;
      double2 w23 = *(const double2*)(wp + 2);
      double wd[4] = {w01.x, w01.y, w23.x, w23.y};
#pragma unroll
      for (int a = 0; a < 4; ++a)
#pragma unroll
        for (int t = 0; t < FT; ++t) acc2[a][t] += wd[a] * fv[t];
    }
    __syncthreads();
  }
  double* red = &fsh[0][0];
#pragma unroll
  for (int a = 0; a < 4; ++a)
#pragma unroll
    for (int t = 0; t < FT; ++t)
      red[(((jg * 8 + t) << 7)) + (dl << 2) + a] = acc2[a][t];
  __syncthreads();
  for (int idx = tid; idx < ND * FT; idx += 256) {
    int t = idx >> 7, d = idx & 127;
    double s = 0.0;
#pragma unroll
    for (int jg2 = 0; jg2 < 8; ++jg2) s += red[((jg2 * 8 + t) << 7) + d];
    float o = (float)s + b2[d];
    float hf = (float)hsh[d][t];
    xsh[t][d] = hf + o;
  }
  __syncthreads();
  if (tid < FT) {
    double sv = 0.0;
    for (int d = 0; d < ND; ++d) sv += (double)xsh[tid][d];
    float m = (float)(sv / 128.0);
    double sq = 0.0;
    for (int d = 0; d < ND; ++d) { float tf = xsh[tid][d] - m; sq += (double)tf * (double)tf; }
    mred[tid] = m;
    sred[tid] = sqrtf((float)(sq / 128.0) + 1e-5f);
  }
  __syncthreads();
  for (int idx = tid; idx < ND * FT; idx += 256) {
    int d = idx & 127, t = idx >> 7;
    float tf = xsh[t][d] - mred[t];
    h[(size_t)(t0 + t) * ND + d] = tf / sred[t] * g[d] + bb[d];
  }
}

// ---------------- decode precompute ----------------
__global__ __launch_bounds__(128) void k_gctx(const float* __restrict__ h, float* __restrict__ gctx) {
  int b = blockIdx.x, d = threadIdx.x;
  double acc = 0.0;
  for (int n = 0; n < NN; ++n) acc += (double)h[(size_t)(b * NN + n) * ND + d];
  gctx[b * ND + d] = (float)(acc / 200.0);
}

#define KT 8
__global__ __launch_bounds__(128) void k_kmat(const float* __restrict__ h, const double* __restrict__ WkT,
                                              float* __restrict__ kmat) {
  const int t0 = blockIdx.x * KT, d = threadIdx.x;
  __shared__ double hsh[ND][KT];
  for (int idx = d; idx < ND * KT; idx += 128) {
    int t = idx & 7, k = idx >> 3;
    hsh[k][t] = (double)h[(size_t)(t0 + t) * ND + k];
  }
  __syncthreads();
  double acc[KT];
#pragma unroll
  for (int t = 0; t < KT; ++t) acc[t] = 0.0;
  for (int k = 0; k < ND; ++k) {
    double w = WkT[(size_t)k * ND + d];
#pragma unroll
    for (int t = 0; t < KT; ++t) acc[t] += w * hsh[k][t];
  }
#pragma unroll
  for (int t = 0; t < KT; ++t)
    kmat[(size_t)(t0 + t) * ND + d] = (float)acc[t];
}

__global__ __launch_bounds__(128) void k_prep1(const float* __restrict__ Wctx, const float* __restrict__ bcap,
                                               const float* __restrict__ Wcap, const float* __restrict__ bctx,
                                               double* __restrict__ t1, double* __restrict__ wu) {
  int k = threadIdx.x;
  double a = 0.0, c = 0.0;
  for (int m = 0; m < ND; ++m) {
    double wc = (double)Wctx[(size_t)k * 384 + 256 + m];
    a += wc * (double)bcap[m];
    c += wc * (double)Wcap[m];
  }
  t1[k] = a + (double)bctx[k];
  wu[k] = c;
}

__global__ __launch_bounds__(128) void k_M(const float* __restrict__ Wq, const float* __restrict__ Wctx,
                                           double* __restrict__ M) {
  int d = blockIdx.x, j = threadIdx.x;
  double acc = 0.0;
  for (int k = 0; k < ND; ++k)
    acc += (double)Wq[(size_t)d * ND + k] * (double)Wctx[(size_t)k * 384 + j];
  M[(size_t)d * ND + j] = acc;
}

__global__ __launch_bounds__(128) void k_u(const float* __restrict__ Wq, const double* __restrict__ wu,
                                           double* __restrict__ u) {
  int d = threadIdx.x;
  double acc = 0.0;
  for (int k = 0; k < ND; ++k) acc += (double)Wq[(size_t)d * ND + k] * wu[k];
  u[d] = acc;
}

__global__ __launch_bounds__(128) void k_t2(const float* __restrict__ Wctx, const float* __restrict__ gctx,
                                            double* __restrict__ t2) {
  int b = blockIdx.x, k = threadIdx.x;
  double acc = 0.0;
  for (int m = 0; m < ND; ++m)
    acc += (double)Wctx[(size_t)k * 384 + 128 + m] * (double)gctx[b * ND + m];
  t2[(size_t)b * ND + k] = acc;
}

__global__ __launch_bounds__(128) void k_vb(const float* __restrict__ Wq, const double* __restrict__ t2,
                                            const double* __restrict__ t1, double* __restrict__ vb) {
  int b = blockIdx.x, d = threadIdx.x;
  double acc = 0.0;
  for (int k = 0; k < ND; ++k)
    acc += (double)Wq[(size_t)d * ND + k] * (t2[(size_t)b * ND + k] + t1[k]);
  vb[(size_t)b * ND + d] = acc;
}

__global__ __launch_bounds__(256) void k_c01(const float* __restrict__ kmat, const double* __restrict__ vb,
                                             const double* __restrict__ u, float* __restrict__ c0, float* __restrict__ c1) {
  int t = blockIdx.x * 256 + threadIdx.x;
  if (t >= NT) return;
  int b = t / NN;
  double a0 = 0.0, a1 = 0.0;
  for (int d = 0; d < ND; ++d) {
    double km = (double)kmat[(size_t)t * ND + d];
    a0 += km * vb[(size_t)b * ND + d];
    a1 += km * u[d];
  }
  c0[t] = (float)a0;
  c1[t] = (float)a1;
}

// KM -> transposed store KMT[b][j][n] (f32, same rounding as before)
__global__ __launch_bounds__(128) void k_KM(const float* __restrict__ kmat, const double* __restrict__ M,
                                            float* __restrict__ KMT) {
  const int t0 = blockIdx.x * KT, j = threadIdx.x;
  const int b = t0 / NN, toff = t0 % NN;   // 8-token groups never cross b (200 % 8 == 0)
  __shared__ double ksh[ND][KT];
  for (int idx = j; idx < ND * KT; idx += 128) {
    int t = idx & 7, k = idx >> 3;
    ksh[k][t] = (double)kmat[(size_t)(t0 + t) * ND + k];
  }
  __syncthreads();
  double acc[KT];
#pragma unroll
  for (int t = 0; t < KT; ++t) acc[t] = 0.0;
  for (int d = 0; d < ND; ++d) {
    double m = M[(size_t)d * ND + j];
#pragma unroll
    for (int t = 0; t < KT; ++t) acc[t] += ksh[d][t] * m;
  }
#pragma unroll
  for (int t = 0; t < KT; ++t)
    KMT[(size_t)b * ND * NN + (size_t)j * NN + toff + t] = (float)acc[t];
}

// P[b][c][n]: block = (b, 8-c tile); coalesced KMT reads; 8 acc chains; ascending-j order
#define PC 8
__global__ __launch_bounds__(256) void k_P(const float* __restrict__ KMT, const float* __restrict__ h,
                                           float* __restrict__ P) {
  const int blk = blockIdx.x;
  const int b = blk / 25, c0 = (blk % 25) * PC;
  const int tid = threadIdx.x;
  __shared__ double h8[ND][PC];
  for (int idx = tid; idx < ND * PC; idx += 256) {
    int t = idx & 7, j = idx >> 3;
    h8[j][t] = (double)h[(size_t)(b * NN + c0 + t) * ND + j];
  }
  __syncthreads();
  if (tid < NN) {
    double acc[PC];
#pragma unroll
    for (int t = 0; t < PC; ++t) acc[t] = 0.0;
    const float* kb = KMT + (size_t)b * ND * NN + tid;
    for (int j = 0; j < ND; ++j) {
      double km = (double)kb[(size_t)j * NN];
#pragma unroll
      for (int t = 0; t < PC; ++t) acc[t] += km * h8[j][t];
    }
#pragma unroll
    for (int t = 0; t < PC; ++t)
      P[(size_t)(b * NN + c0 + t) * NN + tid] = (float)acc[t];
  }
}

// ---------------- decode: one wave / row, P[b] in LDS, gum prefetched ----------------
__global__ __launch_bounds__(64) void k_decode(const float* __restrict__ P, const float* __restrict__ c0,
                                               const float* __restrict__ c1, const float* __restrict__ dr,
                                               const float* __restrict__ gum, float* __restrict__ out) {
  __shared__ float Psh[NN * NN];  // 156.25 KB
  const int b = blockIdx.x, l = threadIdx.x;
  {
    const float4* src = (const float4*)(P + (size_t)b * NN * NN);
    float4* dst = (float4*)Psh;
    for (int i = l; i < (NN * NN) / 4; i += 64) dst[i] = src[i];
  }
  float drs4[4], c04[4], c14[4];
  int vis4[4];
#pragma unroll
  for (int s = 0; s < 4; ++s) {
    int n = l + 64 * s;
    bool valid = n < NN;
    drs4[s] = valid ? dr[b * NN + n] : 1e9f;
    c04[s] = valid ? c0[b * NN + n] : 0.0f;
    c14[s] = valid ? c1[b * NN + n] : 0.0f;
    vis4[s] = valid ? 0 : 1;
  }
  int cur = 0, done = 0;
  float rem = 1.0f, lpsum = 0.0f;
  if (l == 0) out[(size_t)b * 400] = 0.0f;
  __syncthreads();
  const float SQD = 11.3137084989847603f;
  float gv4[4];
#pragma unroll
  for (int s = 0; s < 4; ++s) {
    int n = l + 64 * s;
    gv4[s] = (n < NN) ? gum[(size_t)0 * NT + b * NN + n] : 0.0f;
  }
  for (int t = 0; t < NSTEP; ++t) {
    float gn4[4];
    if (t + 1 < NSTEP) {
      const float* grow = gum + (size_t)(t + 1) * NT + b * NN;
#pragma unroll
      for (int s = 0; s < 4; ++s) {
        int n = l + 64 * s;
        gn4[s] = (n < NN) ? grow[n] : 0.0f;
      }
    }
    const float* Prow = Psh + cur * NN;
    float Pv4[4];
#pragma unroll
    for (int s = 0; s < 4; ++s) {
      int n = l + 64 * s;
      Pv4[s] = (n < NN) ? Prow[n] : 0.0f;
    }
    bool lf = false, lns = false;
#pragma unroll
    for (int s = 0; s < 4; ++s) {
      int n = l + 64 * s;
      if (n >= 1 && n < NN && !vis4[s]) {
        lns = true;
        if (drs4[s] <= rem) lf = true;
      }
    }
    const int has_feas = (__ballot(lf) != 0ULL);
    const int all_served = (__ballot(lns) == 0ULL);
    const bool at_depot = (cur == 0) && !done, not_depot = (cur != 0) && !done;
    const bool depot_mask = (at_depot && has_feas) || (not_depot && has_feas && !all_served);
    float msk[4], sc[4];
#pragma unroll
    for (int s = 0; s < 4; ++s) {
      int n = l + 64 * s;
      if (n < NN) {
        double sd = (double)Pv4[s] + (double)c04[s] + (double)rem * (double)c14[s];
        float logit = (float)sd / SQD;
        bool infn = vis4[s] || (drs4[s] > rem) || (n == 0 && depot_mask);
        msk[s] = infn ? -1e9f : logit;
        sc[s] = msk[s] + gv4[s];
      } else {
        msk[s] = -3.0e38f;
        sc[s] = -3.0e38f;
      }
    }
    float bs = sc[0]; int bn = l; float bmsk = msk[0]; float mx = msk[0];
#pragma unroll
    for (int s = 1; s < 4; ++s) {
      int n = l + 64 * s;
      if (sc[s] > bs) { bs = sc[s]; bn = n; bmsk = msk[s]; }
      mx = fmaxf(mx, msk[s]);
    }
    for (int off = 1; off < 64; off <<= 1) {
      float os = __shfl_xor(bs, off, 64);
      int on = __shfl_xor(bn, off, 64);
      float ob = __shfl_xor(bmsk, off, 64);
      float om = __shfl_xor(mx, off, 64);
      if (os > bs || (os == bs && on < bn)) { bs = os; bn = on; bmsk = ob; }
      mx = fmaxf(mx, om);
    }
    float e = 0.0f;
#pragma unroll
    for (int s = 0; s < 4; ++s) e += expf(msk[s] - mx);
    for (int off = 1; off < 64; off <<= 1) e += __shfl_xor(e, off, 64);
    int sel = bn;
    float slp = (bmsk - mx) - logf(e);
    bool force = (all_served && cur != 0 && !done) || (not_depot && !has_feas) || done;
    if (force) { sel = 0; slp = 0.0f; }
    if (l == 0) out[(size_t)b * 400 + 1 + t] = (float)sel;
    lpsum += slp;
    bool isd = (sel == 0);
    float cand = drs4[sel >> 6];
    float take = __shfl(cand, sel & 63, 64);
    float nr = isd ? 1.0f : (rem - take);
    rem = fminf(fmaxf(nr, 0.0f), 1.0f);
    if (!isd && (sel & 63) == l) vis4[sel >> 6] = 1;
    if (all_served && sel == 0) done = 1;
    cur = sel;
#pragma unroll
    for (int s = 0; s < 4; ++s) gv4[s] = gn4[s];
  }
  if (l == 0) out[(size_t)NB * 400 + b] = lpsum;
}

// ---------------- host ----------------
extern "C" void kernel_launch(void* const* d_in, const int* in_sizes, int n_in,
                              void* d_out, int out_size, void* d_ws, size_t ws_size,
                              hipStream_t stream) {
  (void)in_sizes; (void)n_in; (void)out_size; (void)ws_size;
  const float* coords = (const float*)d_in[0];
  const float* dem    = (const float*)d_in[1];
  const float* cap    = (const float*)d_in[2];
  const float* eW     = (const float*)d_in[3];
  const float* eb     = (const float*)d_in[4];
  const float* Wqkv   = (const float*)d_in[5];
  const float* bqkv   = (const float*)d_in[6];
  const float* Wo     = (const float*)d_in[7];
  const float* bo     = (const float*)d_in[8];
  const float* W1     = (const float*)d_in[9];
  const float* b1     = (const float*)d_in[10];
  const float* W2     = (const float*)d_in[11];
  const float* b2     = (const float*)d_in[12];
  const float* ln1g   = (const float*)d_in[13];
  const float* ln1b   = (const float*)d_in[14];
  const float* ln2g   = (const float*)d_in[15];
  const float* ln2b   = (const float*)d_in[16];
  const float* Wq     = (const float*)d_in[17];
  const float* Wk     = (const float*)d_in[18];
  const float* Wcap   = (const float*)d_in[19];
  const float* bcap   = (const float*)d_in[20];
  const float* Wctx   = (const float*)d_in[21];
  const float* bctx   = (const float*)d_in[22];

  char* ws = (char*)d_ws;
  size_t off = 0;
  auto take = [&](size_t bytes) -> void* {
    void* p = ws + off;
    off += (bytes + 255) & ~(size_t)255;
    return p;
  };
  float* dr   = (float*)take((size_t)NT * 4);
  float* c0   = (float*)take((size_t)NT * 4);
  float* c1   = (float*)take((size_t)NT * 4);
  float* P    = (float*)take((size_t)NB * NN * NN * 4);
  unsigned* rng = (unsigned*)take((size_t)NSTEP * 2 * 4);
  float* h    = (float*)take((size_t)NT * ND * 4);
  float* qkv  = (float*)take((size_t)NT * 384 * 4);
  float* att  = (float*)take((size_t)NT * ND * 4);
  float* kmat = (float*)take((size_t)NT * ND * 4);
  float* gctx = (float*)take((size_t)NB * ND * 4);
  double* M   = (double*)take((size_t)ND * ND * 8);
  double* u   = (double*)take((size_t)ND * 8);
  double* t1  = (double*)take((size_t)ND * 8);
  double* wu  = (double*)take((size_t)ND * 8);
  double* t2  = (double*)take((size_t)NB * ND * 8);
  double* vb  = (double*)take((size_t)NB * ND * 8);
  double* W1T   = (double*)take((size_t)NL * NF * ND * 8);
  double* W2T   = (double*)take((size_t)NL * NF * ND * 8);
  double* WqkvT = (double*)take((size_t)NL * 384 * ND * 8);
  double* WoT   = (double*)take((size_t)NL * ND * ND * 8);
  double* WkT   = (double*)take((size_t)ND * ND * 8);
  float* KMT = qkv;   // alias: qkv (39.3 MB) dead after attention+oln; KMT = 13.1 MB
  float* gum = h;     // alias: h+qkv region (52 MB) >= gum (41 MB); written after k_P

  k_rng<<<1, 1, 0, stream>>>(rng);
  for (int i = 0; i < NL; ++i) {
    k_trd<<<(NF * ND + 255) / 256, 256, 0, stream>>>(W1 + (size_t)i * NF * ND, W1T + (size_t)i * NF * ND, NF, ND);
    k_trd<<<(NF * ND + 255) / 256, 256, 0, stream>>>(W2 + (size_t)i * ND * NF, W2T + (size_t)i * ND * NF, ND, NF);
    k_trd<<<(384 * ND + 255) / 256, 256, 0, stream>>>(Wqkv + (size_t)i * 384 * ND, WqkvT + (size_t)i * 384 * ND, 384, ND);
    k_trd<<<(ND * ND + 255) / 256, 256, 0, stream>>>(Wo + (size_t)i * ND * ND, WoT + (size_t)i * ND * ND, ND, ND);
  }
  k_trd<<<(ND * ND + 255) / 256, 256, 0, stream>>>(Wk, WkT, ND, ND);
  k_embed<<<(NT * ND) / 256, 256, 0, stream>>>(coords, dem, cap, eW, eb, h, dr);
  for (int i = 0; i < NL; ++i) {
    k_qkv<<<NT / QT, 384, 0, stream>>>(h, WqkvT + (size_t)i * 384 * ND, bqkv + (size_t)i * 384, qkv);
    k_attn<<<NB * NH, 256, 0, stream>>>(qkv, att);
    k_oln<<<NT / OT, 128, 0, stream>>>(att, WoT + (size_t)i * ND * ND, bo + (size_t)i * ND,
                                       ln1g + (size_t)i * ND, ln1b + (size_t)i * ND, h);
    k_ffn<<<NT / FT, 256, 0, stream>>>(h, W1T + (size_t)i * NF * ND, b1 + (size_t)i * NF,
                                       W2T + (size_t)i * ND * NF, b2 + (size_t)i * ND,
                                       ln2g + (size_t)i * ND, ln2b + (size_t)i * ND);
  }
  k_gctx<<<NB, 128, 0, stream>>>(h, gctx);
  k_kmat<<<NT / KT, 128, 0, stream>>>(h, WkT, kmat);
  k_prep1<<<1, 128, 0, stream>>>(Wctx, bcap, Wcap, bctx, t1, wu);
  k_M<<<ND, 128, 0, stream>>>(Wq, Wctx, M);
  k_u<<<1, 128, 0, stream>>>(Wq, wu, u);
  k_t2<<<NB, 128, 0, stream>>>(Wctx, gctx, t2);
  k_vb<<<NB, 128, 0, stream>>>(Wq, t2, t1, vb);
  k_c01<<<NT / 256, 256, 0, stream>>>(kmat, vb, u, c0, c1);
  k_KM<<<NT / KT, 128, 0, stream>>>(kmat, M, KMT);
  k_P<<<NB * 25, 256, 0, stream>>>(KMT, h, P);
  k_gum<<<(NSTEP * NT + 255) / 256, 256, 0, stream>>>(rng, gum);
  k_decode<<<NB, 64, 0, stream>>>(P, c0, c1, dr, gum, (float*)d_out);
}

// Round 11
// 4787.809 us; speedup vs baseline: 1.1081x; 1.1081x over previous
//
#include <hip/hip_runtime.h>
#include <hip/hip_bf16.h>
#include <stdint.h>
#include <math.h>

#define NB 128
#define NN 200
#define ND 128
#define NH 8
#define DH 16
#define NL 3
#define NF 2048
#define NT (NB * NN)
#define NSTEP 399

// ---------------- Threefry-2x32 (JAX-compatible) ----------------
__host__ __device__ inline void tf2x32(unsigned k0, unsigned k1, unsigned x0, unsigned x1,
                                       unsigned* o0, unsigned* o1) {
  unsigned ks[3] = {k0, k1, k0 ^ k1 ^ 0x1BD11BDAu};
  x0 += ks[0]; x1 += ks[1];
  const unsigned R[2][4] = {{13u, 15u, 26u, 6u}, {17u, 29u, 16u, 24u}};
#pragma unroll
  for (int i = 0; i < 5; ++i) {
#pragma unroll
    for (int j = 0; j < 4; ++j) {
      unsigned r = R[i & 1][j];
      x0 += x1;
      x1 = (x1 << r) | (x1 >> (32u - r));
      x1 ^= x0;
    }
    x0 += ks[(i + 1) % 3];
    x1 += ks[(i + 2) % 3] + (unsigned)(i + 1);
  }
  *o0 = x0; *o1 = x1;
}

__global__ void k_rng(unsigned* __restrict__ rng) {
  unsigned k0 = 0u, k1 = 42u;
  for (int t = 0; t < NSTEP; ++t) {
    unsigned a0, a1, s0, s1;
    tf2x32(k0, k1, 0u, 1u, &s0, &s1);
    tf2x32(k0, k1, 0u, 0u, &a0, &a1);
    rng[2 * t] = s0; rng[2 * t + 1] = s1;
    k0 = a0; k1 = a1;
  }
}

__global__ __launch_bounds__(256) void k_gum(const unsigned* __restrict__ rng, float* __restrict__ gum) {
  int idx = blockIdx.x * 256 + threadIdx.x;
  if (idx >= NSTEP * NT) return;
  int t = idx / NT, j = idx - t * NT;
  unsigned o0, o1;
  tf2x32(rng[2 * t], rng[2 * t + 1], 0u, (unsigned)j, &o0, &o1);
  unsigned bits = o0 ^ o1;
  float u01 = __uint_as_float((bits >> 9) | 0x3f800000u) - 1.0f;
  float uu = fmaxf(1.17549435082228751e-38f, u01);
  gum[idx] = (float)(-log(-log((double)uu)));
}

// ---------------- transpose f32->f32 ----------------
__global__ void k_tr(const float* __restrict__ src, float* __restrict__ dst, int R, int C) {
  int i = blockIdx.x * 256 + threadIdx.x;
  if (i >= R * C) return;
  int c = i / R, r = i - c * R;
  dst[i] = src[(size_t)r * C + c];
}

// ---------------- transpose + lossless f32->f64 convert ----------------
__global__ void k_trd(const float* __restrict__ src, double* __restrict__ dst, int R, int C) {
  int i = blockIdx.x * 256 + threadIdx.x;
  if (i >= R * C) return;
  int c = i / R, r = i - c * R;
  dst[i] = (double)src[(size_t)r * C + c];
}

// ---------------- embed ----------------
__global__ void k_embed(const float* __restrict__ coords, const float* __restrict__ dem,
                        const float* __restrict__ cap, const float* __restrict__ eW,
                        const float* __restrict__ eb, float* __restrict__ h, float* __restrict__ dr) {
  int gid = blockIdx.x * blockDim.x + threadIdx.x;
  int t = gid >> 7, d = gid & 127;
  int b = t / NN;
  float drv = dem[t] / cap[b];
  double acc = (double)eW[d * 3] * (double)coords[2 * t]
             + (double)eW[d * 3 + 1] * (double)coords[2 * t + 1]
             + (double)eW[d * 3 + 2] * (double)drv;
  h[gid] = (float)acc + eb[d];
  if (d == 0) dr[t] = drv;
}

// ---------------- qkv: 8 tokens/block, f64 weights (L2-resident, 393 KB) ----------------
#define QT 8
__global__ __launch_bounds__(384) void k_qkv(const float* __restrict__ h, const double* __restrict__ WT,
                                             const float* __restrict__ bias, float* __restrict__ qkv) {
  const int t0 = blockIdx.x * QT, j = threadIdx.x;
  __shared__ double hsh[ND][QT];
  for (int idx = j; idx < ND * QT; idx += 384) {
    int t = idx & 7, k = idx >> 3;
    hsh[k][t] = (double)h[(size_t)(t0 + t) * ND + k];
  }
  __syncthreads();
  double acc[QT];
#pragma unroll
  for (int t = 0; t < QT; ++t) acc[t] = 0.0;
  for (int k = 0; k < ND; ++k) {
    double w = WT[(size_t)k * 384 + j];
#pragma unroll
    for (int t = 0; t < QT; ++t) acc[t] += w * hsh[k][t];
  }
  float bv = bias[j];
#pragma unroll
  for (int t = 0; t < QT; ++t)
    qkv[(size_t)(t0 + t) * 384 + j] = (float)acc[t] + bv;
}

// ---------------- attention: wave-per-qn, ONE barrier ----------------
__global__ __launch_bounds__(256) void k_attn(const float* __restrict__ qkv, float* __restrict__ att) {
  const int b = blockIdx.x / NH, hh = blockIdx.x % NH, tid = threadIdx.x;
  const int lane = tid & 63, w = tid >> 6;
  __shared__ float qsh[NN][DH + 1];
  __shared__ float ksh[NN][DH + 1];
  __shared__ float vsh[NN][DH + 1];
  __shared__ float ashw[4][NN + 8];
  for (int idx = tid; idx < NN * DH; idx += 256) {
    int n = idx / DH, d2 = idx % DH;
    size_t base = (size_t)(b * NN + n) * 384 + hh * DH + d2;
    qsh[n][d2] = qkv[base];
    ksh[n][d2] = qkv[base + ND];
    vsh[n][d2] = qkv[base + 2 * ND];
  }
  __syncthreads();
  const int dd = lane & 15, q4 = lane >> 4;
  for (int qn = w; qn < NN; qn += 4) {
    double qv[DH];
#pragma unroll
    for (int d = 0; d < DH; ++d) qv[d] = (double)qsh[qn][d];
    float sf[4];
#pragma unroll
    for (int s = 0; s < 4; ++s) {
      int n = lane + 64 * s;
      if (n < NN) {
        double a = 0.0;
#pragma unroll
        for (int d = 0; d < DH; ++d) a += qv[d] * (double)ksh[n][d];
        sf[s] = (float)a / 4.0f;
      } else sf[s] = -3.0e38f;
    }
    float m = fmaxf(fmaxf(sf[0], sf[1]), fmaxf(sf[2], sf[3]));
    for (int off = 1; off < 64; off <<= 1) m = fmaxf(m, __shfl_xor(m, off, 64));
    double e[4];
    double esum = 0.0;
#pragma unroll
    for (int s = 0; s < 4; ++s) {
      int n = lane + 64 * s;
      e[s] = (n < NN) ? exp((double)(sf[s] - m)) : 0.0;
      esum += e[s];
    }
    for (int off = 1; off < 64; off <<= 1) esum += __shfl_xor(esum, off, 64);
#pragma unroll
    for (int s = 0; s < 4; ++s) {
      int n = lane + 64 * s;
      if (n < NN) ashw[w][n] = (float)(e[s] / esum);
    }
    double o = 0.0;
    for (int i = 0; i < 50; ++i) {
      int n = q4 * 50 + i;
      o += (double)ashw[w][n] * (double)vsh[n][dd];
    }
    o += __shfl_xor(o, 16, 64);
    o += __shfl_xor(o, 32, 64);
    if (lane < DH)
      att[(size_t)(b * NN + qn) * ND + hh * DH + lane] = (float)o;
  }
}

// ---------------- o-proj + residual + LN1, f64 weights (131 KB) ----------------
#define OT 4
__global__ __launch_bounds__(128) void k_oln(const float* __restrict__ att, const double* __restrict__ WoT,
                                             const float* __restrict__ bo, const float* __restrict__ g,
                                             const float* __restrict__ bb, float* __restrict__ h) {
  const int t0 = blockIdx.x * OT, d = threadIdx.x;
  __shared__ double ash[ND][OT];
  __shared__ float xsh[OT][ND];
  __shared__ float mred[OT], sred[OT];
  for (int idx = d; idx < ND * OT; idx += 128) {
    int t = idx & 3, k = idx >> 2;
    ash[k][t] = (double)att[(size_t)(t0 + t) * ND + k];
  }
  __syncthreads();
  double acc[OT];
#pragma unroll
  for (int t = 0; t < OT; ++t) acc[t] = 0.0;
  for (int k = 0; k < ND; ++k) {
    double w = WoT[(size_t)k * ND + d];
#pragma unroll
    for (int t = 0; t < OT; ++t) acc[t] += w * ash[k][t];
  }
  float bv = bo[d];
#pragma unroll
  for (int t = 0; t < OT; ++t) {
    float o = (float)acc[t] + bv;
    xsh[t][d] = h[(size_t)(t0 + t) * ND + d] + o;
  }
  __syncthreads();
  if (d < OT) {
    double sv = 0.0;
    for (int k = 0; k < ND; ++k) sv += (double)xsh[d][k];
    float m = (float)(sv / 128.0);
    double sq = 0.0;
    for (int k = 0; k < ND; ++k) { float tf = xsh[d][k] - m; sq += (double)tf * (double)tf; }
    mred[d] = m;
    sred[d] = sqrtf((float)(sq / 128.0) + 1e-5f);
  }
  __syncthreads();
#pragma unroll
  for (int t = 0; t < OT; ++t) {
    float tf = xsh[t][d] - mred[t];
    h[(size_t)(t0 + t) * ND + d] = tf / sred[t] * g[d] + bb[d];
  }
}

// ---------------- FFN: W1T f64 (2MB) + W2T f32 (1MB) => 3MB < 4MB L2/XCD ----------------
#define FT 8
#define JC 1024
__global__ __launch_bounds__(256) void k_ffn(float* __restrict__ h, const double* __restrict__ W1T,
                                             const float* __restrict__ b1, const float* __restrict__ W2T,
                                             const float* __restrict__ b2, const float* __restrict__ g,
                                             const float* __restrict__ bb) {
  const int t0 = blockIdx.x * FT, tid = threadIdx.x;
  __shared__ double hsh[ND][FT];
  __shared__ double fsh[FT][JC];
  __shared__ float xsh[FT][ND];
  __shared__ float mred[FT], sred[FT];
  for (int idx = tid; idx < ND * FT; idx += 256) {
    int t = idx & 7, k = idx >> 3;
    hsh[k][t] = (double)h[(size_t)(t0 + t) * ND + k];
  }
  __syncthreads();
  const int jg = tid >> 5, dl = tid & 31;
  double acc2[4][FT];
#pragma unroll
  for (int a = 0; a < 4; ++a)
#pragma unroll
    for (int t = 0; t < FT; ++t) acc2[a][t] = 0.0;
  for (int c = 0; c < 2; ++c) {
    // ---- phase 1: f64 weights, zero cvt ----
    {
      const int j0 = tid * 4;
      double acc[4][FT];
#pragma unroll
      for (int a = 0; a < 4; ++a)
#pragma unroll
        for (int t = 0; t < FT; ++t) acc[a][t] = 0.0;
      for (int k = 0; k < ND; ++k) {
        double hv[FT];
#pragma unroll
        for (int t = 0; t < FT; ++t) hv[t] = hsh[k][t];
        const double* wp = W1T + (size_t)k * NF + c * JC + j0;
        double2 wa = *(const double2*)wp;
        double2 wb = *(const double2*)(wp + 2);
        double wd[4] = {wa.x, wa.y, wb.x, wb.y};
#pragma unroll
        for (int a = 0; a < 4; ++a)
#pragma unroll
          for (int t = 0; t < FT; ++t) acc[a][t] += wd[a] * hv[t];
      }
#pragma unroll
      for (int a = 0; a < 4; ++a) {
        float bv = b1[c * JC + j0 + a];
#pragma unroll
        for (int t = 0; t < FT; ++t) {
          float f = (float)acc[a][t] + bv;   // f32 round at tensor boundary (exact)
          fsh[t][j0 + a] = (double)fmaxf(f, 0.0f);
        }
      }
    }
    __syncthreads();
    // ---- phase 2: f32 weights (cvt 4 per 32 FMA), bank-rotated jj ----
    for (int i = 0; i < 128; ++i) {
      int jj = (jg << 7) | ((i + jg) & 127);
      int j = c * JC + jj;
      double fv[FT];
#pragma unroll
      for (int t = 0; t < FT; ++t) fv[t] = fsh[t][jj];
      float4 wv = *(const float4*)(W2T + (size_t)j * ND + (dl << 2));
      double wd[4] = {(double)wv.x, (double)wv.y, (double)wv.z, (double)wv.w};
#pragma unroll
      for (int a = 0; a < 4; ++a)
#pragma unroll
        for (int t = 0; t < FT; ++t) acc2[a][t] += wd[a] * fv[t];
    }
    __syncthreads();
  }
  double* red = &fsh[0][0];
#pragma unroll
  for (int a = 0; a < 4; ++a)
#pragma unroll
    for (int t = 0; t < FT; ++t)
      red[(((jg * 8 + t) << 7)) + (dl << 2) + a] = acc2[a][t];
  __syncthreads();
  for (int idx = tid; idx < ND * FT; idx += 256) {
    int t = idx >> 7, d = idx & 127;
    double s = 0.0;
#pragma unroll
    for (int jg2 = 0; jg2 < 8; ++jg2) s += red[((jg2 * 8 + t) << 7) + d];
    float o = (float)s + b2[d];
    float hf = (float)hsh[d][t];
    xsh[t][d] = hf + o;
  }
  __syncthreads();
  if (tid < FT) {
    double sv = 0.0;
    for (int d = 0; d < ND; ++d) sv += (double)xsh[tid][d];
    float m = (float)(sv / 128.0);
    double sq = 0.0;
    for (int d = 0; d < ND; ++d) { float tf = xsh[tid][d] - m; sq += (double)tf * (double)tf; }
    mred[tid] = m;
    sred[tid] = sqrtf((float)(sq / 128.0) + 1e-5f);
  }
  __syncthreads();
  for (int idx = tid; idx < ND * FT; idx += 256) {
    int d = idx & 127, t = idx >> 7;
    float tf = xsh[t][d] - mred[t];
    h[(size_t)(t0 + t) * ND + d] = tf / sred[t] * g[d] + bb[d];
  }
}

// ---------------- decode precompute ----------------
__global__ __launch_bounds__(128) void k_gctx(const float* __restrict__ h, float* __restrict__ gctx) {
  int b = blockIdx.x, d = threadIdx.x;
  double acc = 0.0;
  for (int n = 0; n < NN; ++n) acc += (double)h[(size_t)(b * NN + n) * ND + d];
  gctx[b * ND + d] = (float)(acc / 200.0);
}

#define KT 8
__global__ __launch_bounds__(128) void k_kmat(const float* __restrict__ h, const double* __restrict__ WkT,
                                              float* __restrict__ kmat) {
  const int t0 = blockIdx.x * KT, d = threadIdx.x;
  __shared__ double hsh[ND][KT];
  for (int idx = d; idx < ND * KT; idx += 128) {
    int t = idx & 7, k = idx >> 3;
    hsh[k][t] = (double)h[(size_t)(t0 + t) * ND + k];
  }
  __syncthreads();
  double acc[KT];
#pragma unroll
  for (int t = 0; t < KT; ++t) acc[t] = 0.0;
  for (int k = 0; k < ND; ++k) {
    double w = WkT[(size_t)k * ND + d];
#pragma unroll
    for (int t = 0; t < KT; ++t) acc[t] += w * hsh[k][t];
  }
#pragma unroll
  for (int t = 0; t < KT; ++t)
    kmat[(size_t)(t0 + t) * ND + d] = (float)acc[t];
}

__global__ __launch_bounds__(128) void k_prep1(const float* __restrict__ Wctx, const float* __restrict__ bcap,
                                               const float* __restrict__ Wcap, const float* __restrict__ bctx,
                                               double* __restrict__ t1, double* __restrict__ wu) {
  int k = threadIdx.x;
  double a = 0.0, c = 0.0;
  for (int m = 0; m < ND; ++m) {
    double wc = (double)Wctx[(size_t)k * 384 + 256 + m];
    a += wc * (double)bcap[m];
    c += wc * (double)Wcap[m];
  }
  t1[k] = a + (double)bctx[k];
  wu[k] = c;
}

__global__ __launch_bounds__(128) void k_M(const float* __restrict__ Wq, const float* __restrict__ Wctx,
                                           double* __restrict__ M) {
  int d = blockIdx.x, j = threadIdx.x;
  double acc = 0.0;
  for (int k = 0; k < ND; ++k)
    acc += (double)Wq[(size_t)d * ND + k] * (double)Wctx[(size_t)k * 384 + j];
  M[(size_t)d * ND + j] = acc;
}

__global__ __launch_bounds__(128) void k_u(const float* __restrict__ Wq, const double* __restrict__ wu,
                                           double* __restrict__ u) {
  int d = threadIdx.x;
  double acc = 0.0;
  for (int k = 0; k < ND; ++k) acc += (double)Wq[(size_t)d * ND + k] * wu[k];
  u[d] = acc;
}

__global__ __launch_bounds__(128) void k_t2(const float* __restrict__ Wctx, const float* __restrict__ gctx,
                                            double* __restrict__ t2) {
  int b = blockIdx.x, k = threadIdx.x;
  double acc = 0.0;
  for (int m = 0; m < ND; ++m)
    acc += (double)Wctx[(size_t)k * 384 + 128 + m] * (double)gctx[b * ND + m];
  t2[(size_t)b * ND + k] = acc;
}

__global__ __launch_bounds__(128) void k_vb(const float* __restrict__ Wq, const double* __restrict__ t2,
                                            const double* __restrict__ t1, double* __restrict__ vb) {
  int b = blockIdx.x, d = threadIdx.x;
  double acc = 0.0;
  for (int k = 0; k < ND; ++k)
    acc += (double)Wq[(size_t)d * ND + k] * (t2[(size_t)b * ND + k] + t1[k]);
  vb[(size_t)b * ND + d] = acc;
}

__global__ __launch_bounds__(256) void k_c01(const float* __restrict__ kmat, const double* __restrict__ vb,
                                             const double* __restrict__ u, float* __restrict__ c0, float* __restrict__ c1) {
  int t = blockIdx.x * 256 + threadIdx.x;
  if (t >= NT) return;
  int b = t / NN;
  double a0 = 0.0, a1 = 0.0;
  for (int d = 0; d < ND; ++d) {
    double km = (double)kmat[(size_t)t * ND + d];
    a0 += km * vb[(size_t)b * ND + d];
    a1 += km * u[d];
  }
  c0[t] = (float)a0;
  c1[t] = (float)a1;
}

// KM -> transposed store KMT[b][j][n]
__global__ __launch_bounds__(128) void k_KM(const float* __restrict__ kmat, const double* __restrict__ M,
                                            float* __restrict__ KMT) {
  const int t0 = blockIdx.x * KT, j = threadIdx.x;
  const int b = t0 / NN, toff = t0 % NN;
  __shared__ double ksh[ND][KT];
  for (int idx = j; idx < ND * KT; idx += 128) {
    int t = idx & 7, k = idx >> 3;
    ksh[k][t] = (double)kmat[(size_t)(t0 + t) * ND + k];
  }
  __syncthreads();
  double acc[KT];
#pragma unroll
  for (int t = 0; t < KT; ++t) acc[t] = 0.0;
  for (int d = 0; d < ND; ++d) {
    double m = M[(size_t)d * ND + j];
#pragma unroll
    for (int t = 0; t < KT; ++t) acc[t] += ksh[d][t] * m;
  }
#pragma unroll
  for (int t = 0; t < KT; ++t)
    KMT[(size_t)b * ND * NN + (size_t)j * NN + toff + t] = (float)acc[t];
}

// P[b][c][n]: coalesced KMT reads; 8 acc chains; ascending-j order
#define PC 8
__global__ __launch_bounds__(256) void k_P(const float* __restrict__ KMT, const float* __restrict__ h,
                                           float* __restrict__ P) {
  const int blk = blockIdx.x;
  const int b = blk / 25, c0 = (blk % 25) * PC;
  const int tid = threadIdx.x;
  __shared__ double h8[ND][PC];
  for (int idx = tid; idx < ND * PC; idx += 256) {
    int t = idx & 7, j = idx >> 3;
    h8[j][t] = (double)h[(size_t)(b * NN + c0 + t) * ND + j];
  }
  __syncthreads();
  if (tid < NN) {
    double acc[PC];
#pragma unroll
    for (int t = 0; t < PC; ++t) acc[t] = 0.0;
    const float* kb = KMT + (size_t)b * ND * NN + tid;
    for (int j = 0; j < ND; ++j) {
      double km = (double)kb[(size_t)j * NN];
#pragma unroll
      for (int t = 0; t < PC; ++t) acc[t] += km * h8[j][t];
    }
#pragma unroll
    for (int t = 0; t < PC; ++t)
      P[(size_t)(b * NN + c0 + t) * NN + tid] = (float)acc[t];
  }
}

// ---------------- decode: one wave / row, P[b] in LDS, gum prefetched ----------------
__global__ __launch_bounds__(64) void k_decode(const float* __restrict__ P, const float* __restrict__ c0,
                                               const float* __restrict__ c1, const float* __restrict__ dr,
                                               const float* __restrict__ gum, float* __restrict__ out) {
  __shared__ float Psh[NN * NN];  // 156.25 KB
  const int b = blockIdx.x, l = threadIdx.x;
  {
    const float4* src = (const float4*)(P + (size_t)b * NN * NN);
    float4* dst = (float4*)Psh;
    for (int i = l; i < (NN * NN) / 4; i += 64) dst[i] = src[i];
  }
  float drs4[4], c04[4], c14[4];
  int vis4[4];
#pragma unroll
  for (int s = 0; s < 4; ++s) {
    int n = l + 64 * s;
    bool valid = n < NN;
    drs4[s] = valid ? dr[b * NN + n] : 1e9f;
    c04[s] = valid ? c0[b * NN + n] : 0.0f;
    c14[s] = valid ? c1[b * NN + n] : 0.0f;
    vis4[s] = valid ? 0 : 1;
  }
  int cur = 0, done = 0;
  float rem = 1.0f, lpsum = 0.0f;
  if (l == 0) out[(size_t)b * 400] = 0.0f;
  __syncthreads();
  const float SQD = 11.3137084989847603f;
  float gv4[4];
#pragma unroll
  for (int s = 0; s < 4; ++s) {
    int n = l + 64 * s;
    gv4[s] = (n < NN) ? gum[(size_t)0 * NT + b * NN + n] : 0.0f;
  }
  for (int t = 0; t < NSTEP; ++t) {
    float gn4[4];
    if (t + 1 < NSTEP) {
      const float* grow = gum + (size_t)(t + 1) * NT + b * NN;
#pragma unroll
      for (int s = 0; s < 4; ++s) {
        int n = l + 64 * s;
        gn4[s] = (n < NN) ? grow[n] : 0.0f;
      }
    }
    const float* Prow = Psh + cur * NN;
    float Pv4[4];
#pragma unroll
    for (int s = 0; s < 4; ++s) {
      int n = l + 64 * s;
      Pv4[s] = (n < NN) ? Prow[n] : 0.0f;
    }
    bool lf = false, lns = false;
#pragma unroll
    for (int s = 0; s < 4; ++s) {
      int n = l + 64 * s;
      if (n >= 1 && n < NN && !vis4[s]) {
        lns = true;
        if (drs4[s] <= rem) lf = true;
      }
    }
    const int has_feas = (__ballot(lf) != 0ULL);
    const int all_served = (__ballot(lns) == 0ULL);
    const bool at_depot = (cur == 0) && !done, not_depot = (cur != 0) && !done;
    const bool depot_mask = (at_depot && has_feas) || (not_depot && has_feas && !all_served);
    float msk[4], sc[4];
#pragma unroll
    for (int s = 0; s < 4; ++s) {
      int n = l + 64 * s;
      if (n < NN) {
        double sd = (double)Pv4[s] + (double)c04[s] + (double)rem * (double)c14[s];
        float logit = (float)sd / SQD;
        bool infn = vis4[s] || (drs4[s] > rem) || (n == 0 && depot_mask);
        msk[s] = infn ? -1e9f : logit;
        sc[s] = msk[s] + gv4[s];
      } else {
        msk[s] = -3.0e38f;
        sc[s] = -3.0e38f;
      }
    }
    float bs = sc[0]; int bn = l; float bmsk = msk[0]; float mx = msk[0];
#pragma unroll
    for (int s = 1; s < 4; ++s) {
      int n = l + 64 * s;
      if (sc[s] > bs) { bs = sc[s]; bn = n; bmsk = msk[s]; }
      mx = fmaxf(mx, msk[s]);
    }
    for (int off = 1; off < 64; off <<= 1) {
      float os = __shfl_xor(bs, off, 64);
      int on = __shfl_xor(bn, off, 64);
      float ob = __shfl_xor(bmsk, off, 64);
      float om = __shfl_xor(mx, off, 64);
      if (os > bs || (os == bs && on < bn)) { bs = os; bn = on; bmsk = ob; }
      mx = fmaxf(mx, om);
    }
    float e = 0.0f;
#pragma unroll
    for (int s = 0; s < 4; ++s) e += expf(msk[s] - mx);
    for (int off = 1; off < 64; off <<= 1) e += __shfl_xor(e, off, 64);
    int sel = bn;
    float slp = (bmsk - mx) - logf(e);
    bool force = (all_served && cur != 0 && !done) || (not_depot && !has_feas) || done;
    if (force) { sel = 0; slp = 0.0f; }
    if (l == 0) out[(size_t)b * 400 + 1 + t] = (float)sel;
    lpsum += slp;
    bool isd = (sel == 0);
    float cand = drs4[sel >> 6];
    float take = __shfl(cand, sel & 63, 64);
    float nr = isd ? 1.0f : (rem - take);
    rem = fminf(fmaxf(nr, 0.0f), 1.0f);
    if (!isd && (sel & 63) == l) vis4[sel >> 6] = 1;
    if (all_served && sel == 0) done = 1;
    cur = sel;
#pragma unroll
    for (int s = 0; s < 4; ++s) gv4[s] = gn4[s];
  }
  if (l == 0) out[(size_t)NB * 400 + b] = lpsum;
}

// ---------------- host ----------------
extern "C" void kernel_launch(void* const* d_in, const int* in_sizes, int n_in,
                              void* d_out, int out_size, void* d_ws, size_t ws_size,
                              hipStream_t stream) {
  (void)in_sizes; (void)n_in; (void)out_size; (void)ws_size;
  const float* coords = (const float*)d_in[0];
  const float* dem    = (const float*)d_in[1];
  const float* cap    = (const float*)d_in[2];
  const float* eW     = (const float*)d_in[3];
  const float* eb     = (const float*)d_in[4];
  const float* Wqkv   = (const float*)d_in[5];
  const float* bqkv   = (const float*)d_in[6];
  const float* Wo     = (const float*)d_in[7];
  const float* bo     = (const float*)d_in[8];
  const float* W1     = (const float*)d_in[9];
  const float* b1     = (const float*)d_in[10];
  const float* W2     = (const float*)d_in[11];
  const float* b2     = (const float*)d_in[12];
  const float* ln1g   = (const float*)d_in[13];
  const float* ln1b   = (const float*)d_in[14];
  const float* ln2g   = (const float*)d_in[15];
  const float* ln2b   = (const float*)d_in[16];
  const float* Wq     = (const float*)d_in[17];
  const float* Wk     = (const float*)d_in[18];
  const float* Wcap   = (const float*)d_in[19];
  const float* bcap   = (const float*)d_in[20];
  const float* Wctx   = (const float*)d_in[21];
  const float* bctx   = (const float*)d_in[22];

  char* ws = (char*)d_ws;
  size_t off = 0;
  auto take = [&](size_t bytes) -> void* {
    void* p = ws + off;
    off += (bytes + 255) & ~(size_t)255;
    return p;
  };
  float* dr   = (float*)take((size_t)NT * 4);
  float* c0   = (float*)take((size_t)NT * 4);
  float* c1   = (float*)take((size_t)NT * 4);
  float* P    = (float*)take((size_t)NB * NN * NN * 4);
  unsigned* rng = (unsigned*)take((size_t)NSTEP * 2 * 4);
  float* h    = (float*)take((size_t)NT * ND * 4);
  float* qkv  = (float*)take((size_t)NT * 384 * 4);
  float* att  = (float*)take((size_t)NT * ND * 4);
  float* kmat = (float*)take((size_t)NT * ND * 4);
  float* gctx = (float*)take((size_t)NB * ND * 4);
  double* M   = (double*)take((size_t)ND * ND * 8);
  double* u   = (double*)take((size_t)ND * 8);
  double* t1  = (double*)take((size_t)ND * 8);
  double* wu  = (double*)take((size_t)ND * 8);
  double* t2  = (double*)take((size_t)NB * ND * 8);
  double* vb  = (double*)take((size_t)NB * ND * 8);
  double* W1T   = (double*)take((size_t)NL * NF * ND * 8);   // f64: phase-1 cvt-free
  float*  W2T   = (float*)take((size_t)NL * NF * ND * 4);    // f32: keep L2 working set < 4 MB
  double* WqkvT = (double*)take((size_t)NL * 384 * ND * 8);
  double* WoT   = (double*)take((size_t)NL * ND * ND * 8);
  double* WkT   = (double*)take((size_t)ND * ND * 8);
  float* KMT = qkv;   // alias: qkv (39.3 MB) dead after attention+oln; KMT = 13.1 MB
  float* gum = h;     // alias: h+qkv region (52 MB) >= gum (41 MB); written after k_P

  k_rng<<<1, 1, 0, stream>>>(rng);
  for (int i = 0; i < NL; ++i) {
    k_trd<<<(NF * ND + 255) / 256, 256, 0, stream>>>(W1 + (size_t)i * NF * ND, W1T + (size_t)i * NF * ND, NF, ND);
    k_tr<<<(NF * ND + 255) / 256, 256, 0, stream>>>(W2 + (size_t)i * ND * NF, W2T + (size_t)i * ND * NF, ND, NF);
    k_trd<<<(384 * ND + 255) / 256, 256, 0, stream>>>(Wqkv + (size_t)i * 384 * ND, WqkvT + (size_t)i * 384 * ND, 384, ND);
    k_trd<<<(ND * ND + 255) / 256, 256, 0, stream>>>(Wo + (size_t)i * ND * ND, WoT + (size_t)i * ND * ND, ND, ND);
  }
  k_trd<<<(ND * ND + 255) / 256, 256, 0, stream>>>(Wk, WkT, ND, ND);
  k_embed<<<(NT * ND) / 256, 256, 0, stream>>>(coords, dem, cap, eW, eb, h, dr);
  for (int i = 0; i < NL; ++i) {
    k_qkv<<<NT / QT, 384, 0, stream>>>(h, WqkvT + (size_t)i * 384 * ND, bqkv + (size_t)i * 384, qkv);
    k_attn<<<NB * NH, 256, 0, stream>>>(qkv, att);
    k_oln<<<NT / OT, 128, 0, stream>>>(att, WoT + (size_t)i * ND * ND, bo + (size_t)i * ND,
                                       ln1g + (size_t)i * ND, ln1b + (size_t)i * ND, h);
    k_ffn<<<NT / FT, 256, 0, stream>>>(h, W1T + (size_t)i * NF * ND, b1 + (size_t)i * NF,
                                       W2T + (size_t)i * ND * NF, b2 + (size_t)i * ND,
                                       ln2g + (size_t)i * ND, ln2b + (size_t)i * ND);
  }
  k_gctx<<<NB, 128, 0, stream>>>(h, gctx);
  k_kmat<<<NT / KT, 128, 0, stream>>>(h, WkT, kmat);
  k_prep1<<<1, 128, 0, stream>>>(Wctx, bcap, Wcap, bctx, t1, wu);
  k_M<<<ND, 128, 0, stream>>>(Wq, Wctx, M);
  k_u<<<1, 128, 0, stream>>>(Wq, wu, u);
  k_t2<<<NB, 128, 0, stream>>>(Wctx, gctx, t2);
  k_vb<<<NB, 128, 0, stream>>>(Wq, t2, t1, vb);
  k_c01<<<NT / 256, 256, 0, stream>>>(kmat, vb, u, c0, c1);
  k_KM<<<NT / KT, 128, 0, stream>>>(kmat, M, KMT);
  k_P<<<NB * 25, 256, 0, stream>>>(KMT, h, P);
  k_gum<<<(NSTEP * NT + 255) / 256, 256, 0, stream>>>(rng, gum);
  k_decode<<<NB, 64, 0, stream>>>(P, c0, c1, dr, gum, (float*)d_out);
}